// Round 7
// baseline (3114.375 us; speedup 1.0000x reference)
//
#include <hip/hip_runtime.h>

// Mandelbrot escape-time counts — bit-exact (R6-proven fused-op pattern) plus
// work reduction: closed-form interior shortcut + survivor compaction.
//
// Proven arithmetic (absmax=0 in R6), pinned with inline asm:
//   zi2 = fl32(zi*zi); mag = fma(zr,zr,zi2)
//   nr  = fl32(fma(zr,zr,-zi2) + cr)
//   zi' = fma(2*zr, zi, ci)          (2*zr via exact add)
//   sticky act, cnt += act           (integers <= 256 exact in f32)
//
// R6 counters: VALU-issue-bound (HBM 1.4%, VGPR 8, occ 91%), 611 us =
// 9 instr x 256 iters x 2 cyc x 256 waves/SIMD at ~2 GHz. Only way down:
// fewer pixel-iterations.
//   Stage A (all px): cardioid/bulb closed-form interior test with 1e-3
//     margin (>=1e-4 from boundary; fp32 orbit noise ~1e-7/step cannot leave
//     the attracting basin => reference provably returns 256) -> write 256.
//     Else 16 bit-exact checks; escaped -> write cnt; survivor -> queue.
//   Stage B: 240 more checks for ~1.3M queued survivors only.
// Work: 256M + ~312M px-iters vs 4096M monolithic (~7x less).
//
// d_ws layout: [0,4) atomic counter | [1024,+cap*16) float4 {zr,zi,cr,ci}
// | [+cap*16, +cap*20) int idx. Queue overflow (cap exceeded — never in
// practice): lane finishes its remaining 240 iters inline. ws too small:
// monolithic R6 fallback. Queue ORDER is nondeterministic (atomics) but
// per-pixel VALUES are deterministic -> graph replay safe.

#define MAX_ITERS 256

__device__ __forceinline__ float mul32(float a, float b) {
    float d; asm("v_mul_f32 %0, %1, %2" : "=v"(d) : "v"(a), "v"(b)); return d;
}
__device__ __forceinline__ float add32(float a, float b) {
    float d; asm("v_add_f32 %0, %1, %2" : "=v"(d) : "v"(a), "v"(b)); return d;
}
__device__ __forceinline__ float fma32(float a, float b, float c) {
    float d; asm("v_fma_f32 %0, %1, %2, %3" : "=v"(d) : "v"(a), "v"(b), "v"(c)); return d;
}
__device__ __forceinline__ float fma32_negc(float a, float b, float c) {
    float d; asm("v_fma_f32 %0, %1, %2, -%3" : "=v"(d) : "v"(a), "v"(b), "v"(c)); return d;
}

// nchecks must be a multiple of 8. Body identical to the R6-proven kernel.
__device__ __forceinline__ void iter_checks(float cr, float ci,
                                            float& zr, float& zi,
                                            float& act, float& cnt, int nchecks)
{
    #pragma unroll 8
    for (int s = 0; s < nchecks; ++s) {
        const float zi2 = mul32(zi, zi);
        const float mag = fma32(zr, zr, zi2);
        act = (mag < 4.0f) ? act : 0.0f;      // sticky escape, NaN-safe
        cnt = cnt + act;                      // exact small-int add
        const float t   = fma32_negc(zr, zr, zi2);
        const float nr  = add32(t, cr);
        const float t2  = add32(zr, zr);
        zi = fma32(t2, zi, ci);
        zr = nr;
    }
}

__global__ void zero_ctr(unsigned* c) { *c = 0u; }

__global__ __launch_bounds__(256) void mandel_stage_a(
    const float* __restrict__ c_real, const float* __restrict__ c_imag,
    float* __restrict__ out, float4* __restrict__ q1, int* __restrict__ q2,
    unsigned* __restrict__ counter, unsigned cap, int n)
{
    int i = blockIdx.x * blockDim.x + threadIdx.x;
    if (i >= n) return;
    const float cr = c_real[i];
    const float ci = c_imag[i];

    // Closed-form safe-interior shortcut (margin 1e-3; plain C math is fine,
    // any rounding variant is absorbed by the margin).
    const float xq = cr - 0.25f;
    const float q  = xq * xq + ci * ci;
    const bool in_card = (q * (q + xq) - 0.25f * ci * ci) < -1e-3f;
    const float xb = cr + 1.0f;
    const bool in_bulb = (xb * xb + ci * ci) < (0.0625f - 1e-3f);
    if (in_card | in_bulb) { out[i] = 256.0f; return; }

    float zr = cr, zi = ci, act = 1.0f, cnt = 0.0f;
    iter_checks(cr, ci, zr, zi, act, cnt, 16);   // checks z_0..z_15
    if (act != 0.0f) {                           // survivor: z_16, cnt==16
        const unsigned slot = atomicAdd(counter, 1u);
        if (slot < cap) {
            q1[slot] = make_float4(zr, zi, cr, ci);
            q2[slot] = i;
            return;
        }
        iter_checks(cr, ci, zr, zi, act, cnt, 240);  // overflow: finish inline
    }
    out[i] = cnt;
}

__global__ __launch_bounds__(256) void mandel_stage_b(
    float* __restrict__ out, const float4* __restrict__ q1,
    const int* __restrict__ q2, const unsigned* __restrict__ counter,
    unsigned cap, unsigned total_threads)
{
    unsigned nq = *counter;
    if (nq > cap) nq = cap;
    for (unsigned j = blockIdx.x * blockDim.x + threadIdx.x; j < nq;
         j += total_threads) {
        const float4 rec = q1[j];
        const int idx = q2[j];
        float zr = rec.x, zi = rec.y;
        const float cr = rec.z, ci = rec.w;
        float act = 1.0f, cnt = 16.0f;
        iter_checks(cr, ci, zr, zi, act, cnt, 240);  // checks z_16..z_255
        out[idx] = cnt;
    }
}

// Fallback: the R6-proven monolithic kernel (used only if d_ws is tiny).
__global__ __launch_bounds__(256) void mandel_mono(
    const float* __restrict__ c_real, const float* __restrict__ c_imag,
    float* __restrict__ out, int n)
{
    int i = blockIdx.x * blockDim.x + threadIdx.x;
    if (i >= n) return;
    const float cr = c_real[i], ci = c_imag[i];
    float zr = cr, zi = ci, act = 1.0f, cnt = 0.0f;
    iter_checks(cr, ci, zr, zi, act, cnt, MAX_ITERS);
    out[i] = cnt;
}

extern "C" void kernel_launch(void* const* d_in, const int* in_sizes, int n_in,
                              void* d_out, int out_size, void* d_ws, size_t ws_size,
                              hipStream_t stream)
{
    const float* c_real = (const float*)d_in[0];
    const float* c_imag = (const float*)d_in[1];
    float* out = (float*)d_out;
    const int n = in_sizes[0];  // 4096*4096
    const int block = 256;
    const int gridA = (n + block - 1) / block;

    unsigned char* ws = (unsigned char*)d_ws;
    const size_t avail = (ws_size > 1024) ? (ws_size - 1024) : 0;
    unsigned cap = (unsigned)(avail / 20u);  // 16B rec + 4B idx per survivor

    if (cap < (1u << 16)) {  // ws too small for compaction: proven fallback
        mandel_mono<<<gridA, block, 0, stream>>>(c_real, c_imag, out, n);
        return;
    }

    unsigned* counter = (unsigned*)ws;
    float4* q1 = (float4*)(ws + 1024);
    int* q2 = (int*)(ws + 1024 + (size_t)cap * 16u);

    zero_ctr<<<1, 1, 0, stream>>>(counter);
    mandel_stage_a<<<gridA, block, 0, stream>>>(c_real, c_imag, out, q1, q2,
                                                counter, cap, n);
    const int gridB = 8192;  // ~2M threads; busy waves get exactly 1 record
    mandel_stage_b<<<gridB, block, 0, stream>>>(out, q1, q2, counter, cap,
                                                (unsigned)(gridB * block));
}

// Round 8
// 256.377 us; speedup vs baseline: 12.1476x; 12.1476x over previous
//
#include <hip/hip_runtime.h>

// Mandelbrot counts — R6-proven bit-exact arithmetic + compaction, with the
// R7 atomic catastrophe fixed.
//
// R7 forensics: stage A 2956us, VALUBusy 2.6% -> waves stalled on the single
// global atomicAdd (used return, divergent branch: compiler did NOT wave-
// coalesce). ~2.2M serialized same-address RMWs ~= 3ms. Fix:
//   * wave-aggregated enqueue: __ballot survivors, ONE atomicAdd per wave
//     (leader lane), broadcast base, lane-rank gives the slot (250k atomics).
//   * 64 striped counters (64B apart, blockIdx&63), each owning a private
//     queue segment -> ~4k atomics/address, overlapped with compute.
// Stage B: 64 segments x 256 blocks; every wave densely packed with
// 240-iteration records (no imbalance).
//
// Proven iter body (absmax=0 in R6/R7), pinned with inline asm:
//   zi2 = fl32(zi*zi); mag = fma(zr,zr,zi2)
//   nr  = fl32(fma(zr,zr,-zi2) + cr); zi' = fma(2*zr, zi, ci)
// Cardioid/bulb shortcut margin 1e-3 (HW-validated in R7, absmax=0).
//
// d_ws: [0,4096) 64 counters (stride 64B) | q1: float4 recs, seg-major
// (seg*seg_cap+slot) | q2: int idx. Segment overflow -> finish inline
// (correct, slower). Tiny ws -> monolithic R6 fallback. Queue order is
// nondeterministic but per-pixel values are deterministic.

#define MAX_ITERS 256

__device__ __forceinline__ float mul32(float a, float b) {
    float d; asm("v_mul_f32 %0, %1, %2" : "=v"(d) : "v"(a), "v"(b)); return d;
}
__device__ __forceinline__ float add32(float a, float b) {
    float d; asm("v_add_f32 %0, %1, %2" : "=v"(d) : "v"(a), "v"(b)); return d;
}
__device__ __forceinline__ float fma32(float a, float b, float c) {
    float d; asm("v_fma_f32 %0, %1, %2, %3" : "=v"(d) : "v"(a), "v"(b), "v"(c)); return d;
}
__device__ __forceinline__ float fma32_negc(float a, float b, float c) {
    float d; asm("v_fma_f32 %0, %1, %2, -%3" : "=v"(d) : "v"(a), "v"(b), "v"(c)); return d;
}

__device__ __forceinline__ void iter_checks(float cr, float ci,
                                            float& zr, float& zi,
                                            float& act, float& cnt, int nchecks)
{
    #pragma unroll 8
    for (int s = 0; s < nchecks; ++s) {
        const float zi2 = mul32(zi, zi);
        const float mag = fma32(zr, zr, zi2);
        act = (mag < 4.0f) ? act : 0.0f;      // sticky escape, NaN-safe
        cnt = cnt + act;                      // exact small-int add
        const float t   = fma32_negc(zr, zr, zi2);
        const float nr  = add32(t, cr);
        const float t2  = add32(zr, zr);
        zi = fma32(t2, zi, ci);
        zr = nr;
    }
}

__global__ void zero_ctrs(unsigned char* ws) {
    if (threadIdx.x < 64) *(unsigned*)(ws + (size_t)threadIdx.x * 64u) = 0u;
}

__global__ __launch_bounds__(256) void mandel_stage_a(
    const float* __restrict__ c_real, const float* __restrict__ c_imag,
    float* __restrict__ out, unsigned char* __restrict__ ws,
    unsigned seg_cap, int n)
{
    int i = blockIdx.x * blockDim.x + threadIdx.x;
    if (i >= n) return;
    const float cr = c_real[i];
    const float ci = c_imag[i];

    // Closed-form safe-interior shortcut (margin absorbs any rounding).
    const float xq = cr - 0.25f;
    const float q  = xq * xq + ci * ci;
    const bool in_card = (q * (q + xq) - 0.25f * ci * ci) < -1e-3f;
    const float xb = cr + 1.0f;
    const bool in_bulb = (xb * xb + ci * ci) < (0.0625f - 1e-3f);
    const bool shortcut = in_card | in_bulb;

    float zr = cr, zi = ci, act = 1.0f, cnt = 0.0f;
    iter_checks(cr, ci, zr, zi, act, cnt, 16);   // checks z_0..z_15

    const bool surv = (!shortcut) && (act != 0.0f);

    // Wave-aggregated enqueue: one atomic per wave, striped over 64 counters.
    const unsigned long long m = __ballot(surv);
    if (m != 0ull) {
        const int lane = __builtin_amdgcn_mbcnt_hi(
            ~0u, __builtin_amdgcn_mbcnt_lo(~0u, 0));
        const int leader = (int)__ffsll((unsigned long long)m) - 1;
        const int seg = blockIdx.x & 63;
        unsigned* ctr = (unsigned*)(ws + (size_t)seg * 64u);
        unsigned base = 0u;
        if (lane == leader) base = atomicAdd(ctr, (unsigned)__popcll(m));
        base = (unsigned)__shfl((int)base, leader, 64);
        if (surv) {
            const unsigned rank = (unsigned)__popcll(m & ((1ull << lane) - 1ull));
            const unsigned slot = base + rank;
            if (slot < seg_cap) {
                float4* q1 = (float4*)(ws + 4096);
                int*    q2 = (int*)(ws + 4096 + (size_t)seg_cap * 64u * 16u);
                const size_t p = (size_t)seg * seg_cap + slot;
                q1[p] = make_float4(zr, zi, cr, ci);
                q2[p] = i;
                return;
            }
            iter_checks(cr, ci, zr, zi, act, cnt, 240);  // overflow: inline
            out[i] = cnt;
            return;
        }
    }
    out[i] = shortcut ? 256.0f : cnt;
}

__global__ __launch_bounds__(256) void mandel_stage_b(
    float* __restrict__ out, const unsigned char* __restrict__ ws,
    unsigned seg_cap, int blocks_per_seg)
{
    const int seg = (int)(blockIdx.x & 63u);
    const int grp = (int)(blockIdx.x >> 6);
    const unsigned cnt_s = *(const unsigned*)(ws + (size_t)seg * 64u);
    const unsigned nq = (cnt_s < seg_cap) ? cnt_s : seg_cap;
    const float4* q1 = (const float4*)(ws + 4096);
    const int*    q2 = (const int*)(ws + 4096 + (size_t)seg_cap * 64u * 16u);
    const unsigned stride = (unsigned)blocks_per_seg * 256u;
    for (unsigned j = (unsigned)grp * 256u + threadIdx.x; j < nq; j += stride) {
        const size_t p = (size_t)seg * seg_cap + j;
        const float4 rec = q1[p];
        const int idx = q2[p];
        float zr = rec.x, zi = rec.y;
        const float cr = rec.z, ci = rec.w;
        float act = 1.0f, cnt = 16.0f;
        iter_checks(cr, ci, zr, zi, act, cnt, 240);  // checks z_16..z_255
        out[idx] = cnt;
    }
}

// Fallback: the R6-proven monolithic kernel (used only if d_ws is tiny).
__global__ __launch_bounds__(256) void mandel_mono(
    const float* __restrict__ c_real, const float* __restrict__ c_imag,
    float* __restrict__ out, int n)
{
    int i = blockIdx.x * blockDim.x + threadIdx.x;
    if (i >= n) return;
    const float cr = c_real[i], ci = c_imag[i];
    float zr = cr, zi = ci, act = 1.0f, cnt = 0.0f;
    iter_checks(cr, ci, zr, zi, act, cnt, MAX_ITERS);
    out[i] = cnt;
}

extern "C" void kernel_launch(void* const* d_in, const int* in_sizes, int n_in,
                              void* d_out, int out_size, void* d_ws, size_t ws_size,
                              hipStream_t stream)
{
    const float* c_real = (const float*)d_in[0];
    const float* c_imag = (const float*)d_in[1];
    float* out = (float*)d_out;
    const int n = in_sizes[0];  // 4096*4096
    const int block = 256;
    const int gridA = (n + block - 1) / block;

    unsigned char* ws = (unsigned char*)d_ws;
    const size_t avail = (ws_size > 4096) ? (ws_size - 4096) : 0;
    unsigned seg_cap = (unsigned)(avail / (64u * 20u));  // 20B/record, 64 segs

    if (seg_cap < 1024u) {  // ws too small for compaction: proven fallback
        mandel_mono<<<gridA, block, 0, stream>>>(c_real, c_imag, out, n);
        return;
    }

    zero_ctrs<<<1, 64, 0, stream>>>(ws);
    mandel_stage_a<<<gridA, block, 0, stream>>>(c_real, c_imag, out, ws,
                                                seg_cap, n);
    const int blocks_per_seg = 256;  // 64*256 = 16384 blocks, 64k threads/seg
    mandel_stage_b<<<64 * blocks_per_seg, block, 0, stream>>>(out, ws, seg_cap,
                                                              blocks_per_seg);
}